// Round 1
// baseline (815.668 us; speedup 1.0000x reference)
//
#include <hip/hip_runtime.h>

typedef unsigned short u16;
typedef unsigned int u32;
typedef __attribute__((ext_vector_type(8))) short short8;
typedef __attribute__((ext_vector_type(4))) float f32x4;

__device__ __forceinline__ float b2f(u32 u) {
    union { u32 i; float f; } x; x.i = u << 16; return x.f;
}
__device__ __forceinline__ u16 f2b(float f) {
    union { float f; u32 i; } x; x.f = f;
    u32 u = x.i;
    u += 0x7fffu + ((u >> 16) & 1u);
    return (u16)(u >> 16);
}
__device__ __forceinline__ u32 pack2(float a, float b) {
    return (u32)f2b(a) | ((u32)f2b(b) << 16);
}
__device__ __forceinline__ void gl_lds16(const u16* g, u16* l) {
    __builtin_amdgcn_global_load_lds(
        (const __attribute__((address_space(1))) u32*)g,
        (__attribute__((address_space(3))) u32*)l, 16, 0, 0);
}

// ---------------- rope tables: cos/sin for 16384 positions x 32 pairs ----------------
__global__ void rope_tab(float* __restrict__ cosT, float* __restrict__ sinT) {
    int idx = blockIdx.x * 256 + threadIdx.x;      // < 524288
    int n = idx >> 5, i = idx & 31;
    float inv = exp2f(-(float)i * 0.41524101186091903f);  // log2(10000)/32
    float ang = (float)n * inv;
    float s, c;
    sincosf(ang, &s, &c);
    cosT[idx] = c; sinT[idx] = s;
}

// ---------------- weight convert + transpose to bf16 N-major ----------------
__global__ void conv_w(const float* __restrict__ Wq, const float* __restrict__ Wkv,
                       const float* __restrict__ Wo,
                       u16* __restrict__ wqkvT, u16* __restrict__ woT) {
    int idx = blockIdx.x * 256 + threadIdx.x;      // < 1048576
    if (idx < 786432) {                            // 1536 x 512
        int n = idx >> 9, k = idx & 511;
        float v = (n < 512) ? Wq[k * 512 + n] : Wkv[k * 1024 + (n - 512)];
        wqkvT[idx] = f2b(v);
    } else {
        int j = idx - 786432;                      // 512 x 512
        int n = j >> 9, k = j & 511;
        woT[j] = f2b(Wo[k * 512 + n]);
    }
}

// ---------------- RMSNorm: one wave per 512-col row, bf16 out ----------------
__launch_bounds__(256)
__global__ void rmsnorm_k(const float* __restrict__ x, const float* __restrict__ g,
                          u16* __restrict__ xn) {
    int row  = blockIdx.x * 4 + (threadIdx.x >> 6);
    int lane = threadIdx.x & 63;
    const float4* p = (const float4*)(x + (size_t)row * 512);
    float4 a = p[lane * 2], b = p[lane * 2 + 1];
    float ss = a.x*a.x + a.y*a.y + a.z*a.z + a.w*a.w
             + b.x*b.x + b.y*b.y + b.z*b.z + b.w*b.w;
#pragma unroll
    for (int off = 1; off < 64; off <<= 1) ss += __shfl_xor(ss, off);
    float scale = rsqrtf(ss * (1.0f / 512.0f) + 1.1920929e-07f);
    const float4* gp = (const float4*)g;
    float4 g0 = gp[lane * 2], g1 = gp[lane * 2 + 1];
    uint4 u;
    u.x = pack2(a.x * scale * g0.x, a.y * scale * g0.y);
    u.y = pack2(a.z * scale * g0.z, a.w * scale * g0.w);
    u.z = pack2(b.x * scale * g1.x, b.y * scale * g1.y);
    u.w = pack2(b.z * scale * g1.z, b.w * scale * g1.w);
    *(uint4*)(xn + (size_t)row * 512 + lane * 8) = u;
}

// ---------------- GEMM, M=65536, K=512, m97-style 128x128 tile ----------------
// MODE 0: N=1536 (q|k|v); A-row base switches to reversed batch for n>=512.
//         cols [0,512)->oq bf16, [512,1024)->ok bf16, [1024,1536)->ov bf16 + of fp32 (B,h,N,d)
// MODE 1: N=512, plain fp32 epilogue to of.
template <int MODE>
__launch_bounds__(256)
__global__ void gemm_k512(const u16* __restrict__ A, const u16* __restrict__ Bt,
                          u16* __restrict__ oq, u16* __restrict__ ok,
                          u16* __restrict__ ov, float* __restrict__ of) {
    __shared__ u16 As[128 * 64];
    __shared__ u16 Bs[128 * 64];
    const int tid  = threadIdx.x;
    const int lane = tid & 63, w = tid >> 6;
    const int w0 = w & 1, w1 = w >> 1;
    const int l15 = lane & 15, l4 = lane >> 4;
    const int t0 = blockIdx.x * 128;
    const int n0 = blockIdx.y * 128;
    int arow0 = t0;
    if (MODE == 0 && n0 >= 512) {
        int b = t0 >> 14;
        arow0 = (((b + 2) & 3) << 14) | (t0 & 16383);
    }
    const int lr = lane >> 3;          // row within 8-row chunk
    const int sg = (lane & 7) ^ lr;    // XOR-swizzled global 16B-chunk index

    f32x4 acc[4][4];
#pragma unroll
    for (int i = 0; i < 4; ++i)
#pragma unroll
        for (int j = 0; j < 4; ++j) acc[i][j] = (f32x4){0.f, 0.f, 0.f, 0.f};

    for (int kb = 0; kb < 512; kb += 64) {
        __syncthreads();
#pragma unroll
        for (int c = 0; c < 4; ++c) {
            int ca = w * 4 + c;                    // chunk 0..15 (8 rows each)
            int r  = ca * 8 + lr;
            gl_lds16(A  + (size_t)(arow0 + r) * 512 + kb + sg * 8, &As[ca * 512]);
            gl_lds16(Bt + (size_t)(n0    + r) * 512 + kb + sg * 8, &Bs[ca * 512]);
        }
        __syncthreads();
#pragma unroll
        for (int ksi = 0; ksi < 2; ++ksi) {
            short8 a[4], bfr[4];
#pragma unroll
            for (int mi = 0; mi < 4; ++mi) {
                int row = w0 * 64 + mi * 16 + l15;
                int ch  = (ksi * 4 + l4) ^ (row & 7);
                a[mi] = *(const short8*)&As[row * 64 + ch * 8];
            }
#pragma unroll
            for (int ni = 0; ni < 4; ++ni) {
                int row = w1 * 64 + ni * 16 + l15;
                int ch  = (ksi * 4 + l4) ^ (row & 7);
                bfr[ni] = *(const short8*)&Bs[row * 64 + ch * 8];
            }
#pragma unroll
            for (int mi = 0; mi < 4; ++mi)
#pragma unroll
                for (int ni = 0; ni < 4; ++ni)
                    acc[mi][ni] = __builtin_amdgcn_mfma_f32_16x16x32_bf16(
                        a[mi], bfr[ni], acc[mi][ni], 0, 0, 0);
        }
    }
    // epilogue: C row = (l>>4)*4+reg, col = l&15 within each 16x16 tile
#pragma unroll
    for (int mi = 0; mi < 4; ++mi) {
#pragma unroll
        for (int ni = 0; ni < 4; ++ni) {
#pragma unroll
            for (int r = 0; r < 4; ++r) {
                int grow = t0 + w0 * 64 + mi * 16 + l4 * 4 + r;
                int gcol = n0 + w1 * 64 + ni * 16 + l15;
                float val = acc[mi][ni][r];
                if (MODE == 1) {
                    of[(size_t)grow * 512 + gcol] = val;
                } else {
                    if (gcol < 512) {
                        oq[(size_t)grow * 512 + gcol] = f2b(val);
                    } else if (gcol < 1024) {
                        ok[(size_t)grow * 512 + (gcol - 512)] = f2b(val);
                    } else {
                        int c = gcol - 1024;
                        ov[(size_t)grow * 512 + c] = f2b(val);
                        int bb = grow >> 14, nn = grow & 16383;
                        of[((size_t)(bb * 8 + (c >> 6)) << 20) + (size_t)nn * 64 + (c & 63)] = val;
                    }
                }
            }
        }
    }
}

// ---------------- windowed attention: one block per (b, window, head) ----------------
// Q 64x64, K/V 68x64 (4 persistent-mem + 64 tokens), RoPE fused at staging.
__launch_bounds__(256)
__global__ void attn_win(const u16* __restrict__ q_buf, const u16* __restrict__ k_buf,
                         const u16* __restrict__ v_buf, const float* __restrict__ tm,
                         const float* __restrict__ cosT, const float* __restrict__ sinT,
                         u16* __restrict__ o_buf) {
    __shared__ u16 qs[64 * 72];    // [qrow][dh],  stride 72 bf16 (144 B)
    __shared__ u16 ks[80 * 72];    // [key][dh],   rows 0-3 pm, 4-67 tokens, 68-79 zero
    __shared__ u16 vt[64 * 104];   // [dh][key],   stride 104 bf16 (208 B), keys 68-95 zero
    __shared__ u16 ps[64 * 104];   // [qrow][key], exp(S-m); keys 68-95 zero
    const int tid  = threadIdx.x;
    const int lane = tid & 63, w = tid >> 6;
    const int l15 = lane & 15, l4 = lane >> 4;
    const int h = blockIdx.x, wi = blockIdx.y, b = blockIdx.z;
    const int t0 = b * 16384 + wi * 64;

    // phase 0: zero pads (full ps/vt + ks pad rows)
    for (int i = tid; i < 3328; i += 256) { ((u32*)ps)[i] = 0u; ((u32*)vt)[i] = 0u; }
    for (int i = tid; i < 432; i += 256) ((u32*)ks)[2448 + i] = 0u;   // ks rows 68..79
    __syncthreads();

    // phase 1: stage task-memory, Q/K with rope, V transposed
    {
        int r = tid >> 6, d = tid & 63;    // 256 threads == 4x64
        ks[r * 72 + d]   = f2b(tm[(h * 4 + r) * 64 + d]);
        vt[d * 104 + r]  = f2b(tm[2048 + (h * 4 + r) * 64 + d]);
    }
#pragma unroll
    for (int p = tid; p < 2048; p += 256) {
        int row = p >> 5, i = p & 31;
        int n = wi * 64 + row;
        float c = cosT[n * 32 + i], s = sinT[n * 32 + i];
        size_t gbase = (size_t)(t0 + row) * 512 + h * 64 + 2 * i;
        u32 qv = *(const u32*)(q_buf + gbase);
        float x0 = b2f(qv & 0xffffu), x1 = b2f(qv >> 16);
        *(u32*)&qs[row * 72 + 2 * i] = pack2(x0 * c - x1 * s, x1 * c + x0 * s);
        u32 kv = *(const u32*)(k_buf + gbase);
        x0 = b2f(kv & 0xffffu); x1 = b2f(kv >> 16);
        *(u32*)&ks[(row + 4) * 72 + 2 * i] = pack2(x0 * c - x1 * s, x1 * c + x0 * s);
    }
#pragma unroll
    for (int e = tid; e < 4096; e += 256) {
        int row = e >> 6, d = e & 63;
        vt[d * 104 + 4 + row] = v_buf[(size_t)(t0 + row) * 512 + h * 64 + d];
    }
    __syncthreads();

    // phase 2: S = Q K^T (wave w owns q-rows [w*16, w*16+16))
    f32x4 sacc[5];
#pragma unroll
    for (int nt = 0; nt < 5; ++nt) sacc[nt] = (f32x4){0.f, 0.f, 0.f, 0.f};
#pragma unroll
    for (int ksi = 0; ksi < 2; ++ksi) {
        short8 a = *(const short8*)&qs[(w * 16 + l15) * 72 + ksi * 32 + l4 * 8];
#pragma unroll
        for (int nt = 0; nt < 5; ++nt) {
            short8 bfr = *(const short8*)&ks[(nt * 16 + l15) * 72 + ksi * 32 + l4 * 8];
            sacc[nt] = __builtin_amdgcn_mfma_f32_16x16x32_bf16(a, bfr, sacc[nt], 0, 0, 0);
        }
    }
    // softmax (rows = w*16 + l4*4 + r; cols spread over 16 lanes x 5 tiles)
    float inv_l[4];
#pragma unroll
    for (int r = 0; r < 4; ++r) {
        float sv[5];
#pragma unroll
        for (int nt = 0; nt < 5; ++nt) {
            float x = sacc[nt][r] * 0.125f;
            if (nt == 4 && l15 >= 4) x = -1e30f;   // keys >= 68 masked
            sv[nt] = x;
        }
        float m = sv[0];
#pragma unroll
        for (int nt = 1; nt < 5; ++nt) m = fmaxf(m, sv[nt]);
#pragma unroll
        for (int off = 1; off < 16; off <<= 1) m = fmaxf(m, __shfl_xor(m, off));
        float sum = 0.f;
#pragma unroll
        for (int nt = 0; nt < 5; ++nt) { sv[nt] = __expf(sv[nt] - m); sum += sv[nt]; }
#pragma unroll
        for (int off = 1; off < 16; off <<= 1) sum += __shfl_xor(sum, off);
        inv_l[r] = 1.f / sum;
        int prow = w * 16 + l4 * 4 + r;
#pragma unroll
        for (int nt = 0; nt < 5; ++nt) ps[prow * 104 + nt * 16 + l15] = f2b(sv[nt]);
    }
    __syncthreads();

    // phase 3: O = P V  (K-dim padded to 96)
    f32x4 oacc[4];
#pragma unroll
    for (int dt = 0; dt < 4; ++dt) oacc[dt] = (f32x4){0.f, 0.f, 0.f, 0.f};
#pragma unroll
    for (int ksi = 0; ksi < 3; ++ksi) {
        short8 a = *(const short8*)&ps[(w * 16 + l15) * 104 + ksi * 32 + l4 * 8];
#pragma unroll
        for (int dt = 0; dt < 4; ++dt) {
            short8 bfr = *(const short8*)&vt[(dt * 16 + l15) * 104 + ksi * 32 + l4 * 8];
            oacc[dt] = __builtin_amdgcn_mfma_f32_16x16x32_bf16(a, bfr, oacc[dt], 0, 0, 0);
        }
    }
#pragma unroll
    for (int dt = 0; dt < 4; ++dt)
#pragma unroll
        for (int r = 0; r < 4; ++r) {
            int row = w * 16 + l4 * 4 + r;
            o_buf[(size_t)(t0 + row) * 512 + h * 64 + dt * 16 + l15] =
                f2b(oacc[dt][r] * inv_l[r]);
        }
}

// ---------------- launch ----------------
extern "C" void kernel_launch(void* const* d_in, const int* in_sizes, int n_in,
                              void* d_out, int out_size, void* d_ws, size_t ws_size,
                              hipStream_t stream) {
    const float* seq    = (const float*)d_in[0];
    const float* norm_w = (const float*)d_in[5];
    const float* Wq     = (const float*)d_in[6];
    const float* Wkv    = (const float*)d_in[7];
    const float* Wo     = (const float*)d_in[8];
    const float* tmem   = (const float*)d_in[9];
    float* out   = (float*)d_out;
    float* origv = out + 33554432;          // (B=4, h=8, N=16384, d=64)

    char* ws = (char*)d_ws;
    u16* xn    = (u16*)(ws);                 // 64 MB; reused as attn_out after qkv GEMM
    u16* q_buf = (u16*)(ws + 67108864);
    u16* k_buf = (u16*)(ws + 134217728);
    u16* v_buf = (u16*)(ws + 201326592);
    u16* wqkvT = (u16*)(ws + 268435456);     // 1536x512 bf16
    u16* woT   = (u16*)(ws + 268435456 + 1572864);   // 512x512 bf16
    float* cosT = (float*)(ws + 270532608);  // 16384x32
    float* sinT = cosT + 524288;

    rope_tab<<<2048, 256, 0, stream>>>(cosT, sinT);
    conv_w<<<4096, 256, 0, stream>>>(Wq, Wkv, Wo, wqkvT, woT);
    rmsnorm_k<<<16384, 256, 0, stream>>>(seq, norm_w, xn);
    gemm_k512<0><<<dim3(512, 12), 256, 0, stream>>>(xn, wqkvT, q_buf, k_buf, v_buf, origv);
    attn_win<<<dim3(8, 256, 4), 256, 0, stream>>>(q_buf, k_buf, v_buf, tmem, cosT, sinT, xn);
    gemm_k512<1><<<dim3(512, 4), 256, 0, stream>>>(xn, woT, nullptr, nullptr, nullptr, out);
}

// Round 2
// 701.297 us; speedup vs baseline: 1.1631x; 1.1631x over previous
//
#include <hip/hip_runtime.h>

typedef unsigned short u16;
typedef unsigned int u32;
typedef __attribute__((ext_vector_type(8))) short short8;
typedef __attribute__((ext_vector_type(4))) float f32x4;

__device__ __forceinline__ float b2f(u32 u) {
    union { u32 i; float f; } x; x.i = u << 16; return x.f;
}
__device__ __forceinline__ u16 f2b(float f) {
    union { float f; u32 i; } x; x.f = f;
    u32 u = x.i;
    u += 0x7fffu + ((u >> 16) & 1u);
    return (u16)(u >> 16);
}
__device__ __forceinline__ u32 pack2(float a, float b) {
    return (u32)f2b(a) | ((u32)f2b(b) << 16);
}
__device__ __forceinline__ void gl_lds16(const u16* g, u16* l) {
    __builtin_amdgcn_global_load_lds(
        (const __attribute__((address_space(1))) u32*)g,
        (__attribute__((address_space(3))) u32*)l, 16, 0, 0);
}

// ---------------- rope tables: cos/sin for 16384 positions x 32 pairs ----------------
__global__ void rope_tab(float* __restrict__ cosT, float* __restrict__ sinT) {
    int idx = blockIdx.x * 256 + threadIdx.x;      // < 524288
    int n = idx >> 5, i = idx & 31;
    float inv = exp2f(-(float)i * 0.41524101186091903f);  // log2(10000)/32
    float ang = (float)n * inv;
    float s, c;
    sincosf(ang, &s, &c);
    cosT[idx] = c; sinT[idx] = s;
}

// ---------------- weight convert + transpose to bf16 N-major ----------------
__global__ void conv_w(const float* __restrict__ Wq, const float* __restrict__ Wkv,
                       const float* __restrict__ Wo,
                       u16* __restrict__ wqkvT, u16* __restrict__ woT) {
    int idx = blockIdx.x * 256 + threadIdx.x;      // < 1048576
    if (idx < 786432) {                            // 1536 x 512
        int n = idx >> 9, k = idx & 511;
        float v = (n < 512) ? Wq[k * 512 + n] : Wkv[k * 1024 + (n - 512)];
        wqkvT[idx] = f2b(v);
    } else {
        int j = idx - 786432;                      // 512 x 512
        int n = j >> 9, k = j & 511;
        woT[j] = f2b(Wo[k * 512 + n]);
    }
}

// ---------------- RMSNorm: one wave per 512-col row, bf16 out ----------------
__launch_bounds__(256)
__global__ void rmsnorm_k(const float* __restrict__ x, const float* __restrict__ g,
                          u16* __restrict__ xn) {
    int row  = blockIdx.x * 4 + (threadIdx.x >> 6);
    int lane = threadIdx.x & 63;
    const float4* p = (const float4*)(x + (size_t)row * 512);
    float4 a = p[lane * 2], b = p[lane * 2 + 1];
    float ss = a.x*a.x + a.y*a.y + a.z*a.z + a.w*a.w
             + b.x*b.x + b.y*b.y + b.z*b.z + b.w*b.w;
#pragma unroll
    for (int off = 1; off < 64; off <<= 1) ss += __shfl_xor(ss, off);
    float scale = rsqrtf(ss * (1.0f / 512.0f) + 1.1920929e-07f);
    const float4* gp = (const float4*)g;
    float4 g0 = gp[lane * 2], g1 = gp[lane * 2 + 1];
    uint4 u;
    u.x = pack2(a.x * scale * g0.x, a.y * scale * g0.y);
    u.y = pack2(a.z * scale * g0.z, a.w * scale * g0.w);
    u.z = pack2(b.x * scale * g1.x, b.y * scale * g1.y);
    u.w = pack2(b.z * scale * g1.z, b.w * scale * g1.w);
    *(uint4*)(xn + (size_t)row * 512 + lane * 8) = u;
}

// ---------------- GEMM, M=65536, K=512, m97-style 128x128 tile ----------------
// 1D grid, XCD-grouped swizzle: all n-tiles of one m-tile share blockIdx%8 so the
// A-slab (128 rows x 512 x 2B = 128 KB) stays in one XCD's 4MB L2.
// MODE 0: N=1536 (q|k|v), 6144 blocks; A-row base switches to reversed batch for n>=512
//         (rev(m) == m mod 8, so rev-slabs land on the same XCD too).
//         cols [0,512)->oq bf16, [512,1024)->ok bf16, [1024,1536)->ov bf16 + of fp32 (B,h,N,d)
// MODE 1: N=512, 2048 blocks, plain fp32 epilogue to of.
template <int MODE>
__launch_bounds__(256)
__global__ void gemm_k512(const u16* __restrict__ A, const u16* __restrict__ Bt,
                          u16* __restrict__ oq, u16* __restrict__ ok,
                          u16* __restrict__ ov, float* __restrict__ of) {
    __shared__ u16 As[128 * 64];
    __shared__ u16 Bs[128 * 64];
    const int tid  = threadIdx.x;
    const int lane = tid & 63, w = tid >> 6;
    const int w0 = w & 1, w1 = w >> 1;
    const int l15 = lane & 15, l4 = lane >> 4;
    const int idx = blockIdx.x;
    const int xcd = idx & 7, rest = idx >> 3;
    int j, mg;
    if (MODE == 0) { j = rest % 12; mg = rest / 12; }
    else           { j = rest & 3;  mg = rest >> 2; }
    const int t0 = (mg * 8 + xcd) * 128;
    const int n0 = j * 128;
    int arow0 = t0;
    if (MODE == 0 && n0 >= 512) {
        int b = t0 >> 14;
        arow0 = (((b + 2) & 3) << 14) | (t0 & 16383);
    }
    const int lr = lane >> 3;          // row within 8-row chunk
    const int sg = (lane & 7) ^ lr;    // XOR-swizzled global 16B-chunk index

    f32x4 acc[4][4];
#pragma unroll
    for (int i = 0; i < 4; ++i)
#pragma unroll
        for (int jj = 0; jj < 4; ++jj) acc[i][jj] = (f32x4){0.f, 0.f, 0.f, 0.f};

    for (int kb = 0; kb < 512; kb += 64) {
        __syncthreads();
#pragma unroll
        for (int c = 0; c < 4; ++c) {
            int ca = w * 4 + c;                    // chunk 0..15 (8 rows each)
            int r  = ca * 8 + lr;
            gl_lds16(A  + (size_t)(arow0 + r) * 512 + kb + sg * 8, &As[ca * 512]);
            gl_lds16(Bt + (size_t)(n0    + r) * 512 + kb + sg * 8, &Bs[ca * 512]);
        }
        __syncthreads();
#pragma unroll
        for (int ksi = 0; ksi < 2; ++ksi) {
            short8 a[4], bfr[4];
#pragma unroll
            for (int mi = 0; mi < 4; ++mi) {
                int row = w0 * 64 + mi * 16 + l15;
                int ch  = (ksi * 4 + l4) ^ (row & 7);
                a[mi] = *(const short8*)&As[row * 64 + ch * 8];
            }
#pragma unroll
            for (int ni = 0; ni < 4; ++ni) {
                int row = w1 * 64 + ni * 16 + l15;
                int ch  = (ksi * 4 + l4) ^ (row & 7);
                bfr[ni] = *(const short8*)&Bs[row * 64 + ch * 8];
            }
#pragma unroll
            for (int mi = 0; mi < 4; ++mi)
#pragma unroll
                for (int ni = 0; ni < 4; ++ni)
                    acc[mi][ni] = __builtin_amdgcn_mfma_f32_16x16x32_bf16(
                        a[mi], bfr[ni], acc[mi][ni], 0, 0, 0);
        }
    }
    // epilogue: C row = (l>>4)*4+reg, col = l&15 within each 16x16 tile
#pragma unroll
    for (int mi = 0; mi < 4; ++mi) {
#pragma unroll
        for (int ni = 0; ni < 4; ++ni) {
#pragma unroll
            for (int r = 0; r < 4; ++r) {
                int grow = t0 + w0 * 64 + mi * 16 + l4 * 4 + r;
                int gcol = n0 + w1 * 64 + ni * 16 + l15;
                float val = acc[mi][ni][r];
                if (MODE == 1) {
                    of[(size_t)grow * 512 + gcol] = val;
                } else {
                    if (gcol < 512) {
                        oq[(size_t)grow * 512 + gcol] = f2b(val);
                    } else if (gcol < 1024) {
                        ok[(size_t)grow * 512 + (gcol - 512)] = f2b(val);
                    } else {
                        int c = gcol - 1024;
                        ov[(size_t)grow * 512 + c] = f2b(val);
                        int bb = grow >> 14, nn = grow & 16383;
                        of[((size_t)(bb * 8 + (c >> 6)) << 20) + (size_t)nn * 64 + (c & 63)] = val;
                    }
                }
            }
        }
    }
}

// ---------------- windowed attention: one block per (b, window, head) ----------------
// Q 64x64, K/V 68x64 (4 persistent-mem + 64 tokens), RoPE fused at staging.
__launch_bounds__(256)
__global__ void attn_win(const u16* __restrict__ q_buf, const u16* __restrict__ k_buf,
                         const u16* __restrict__ v_buf, const float* __restrict__ tm,
                         const float* __restrict__ cosT, const float* __restrict__ sinT,
                         u16* __restrict__ o_buf) {
    __shared__ u16 qs[64 * 72];    // [qrow][dh],  stride 72 bf16 (144 B)
    __shared__ u16 ks[80 * 72];    // [key][dh],   rows 0-3 pm, 4-67 tokens, 68-79 zero
    __shared__ u16 vt[64 * 104];   // [dh][key],   stride 104 bf16; keys 68-95 zeroed
    __shared__ u16 ps[64 * 104];   // [qrow][key]; cols 0-95 written in softmax (80-95 = 0)
    const int tid  = threadIdx.x;
    const int lane = tid & 63, w = tid >> 6;
    const int l15 = lane & 15, l4 = lane >> 4;
    const int h = blockIdx.x, wi = blockIdx.y, b = blockIdx.z;
    const int t0 = b * 16384 + wi * 64;

    // zero only what's read-but-unwritten: vt keys 68..95 (14 u32/row), ks rows 68..79
    for (int i = tid; i < 896; i += 256) {
        int d = i / 14, c = i - d * 14;
        *(u32*)&vt[d * 104 + 68 + 2 * c] = 0u;
    }
    for (int i = tid; i < 432; i += 256) ((u32*)ks)[2448 + i] = 0u;   // ks rows 68..79

    // stage task-memory (disjoint from zero regions; no barrier needed yet)
    {
        int r = tid >> 6, d = tid & 63;    // 256 threads == 4x64
        ks[r * 72 + d]   = f2b(tm[(h * 4 + r) * 64 + d]);
        vt[d * 104 + r]  = f2b(tm[2048 + (h * 4 + r) * 64 + d]);
    }
    // stage Q/K with rope
#pragma unroll
    for (int p = tid; p < 2048; p += 256) {
        int row = p >> 5, i = p & 31;
        int n = wi * 64 + row;
        float c = cosT[n * 32 + i], s = sinT[n * 32 + i];
        size_t gbase = (size_t)(t0 + row) * 512 + h * 64 + 2 * i;
        u32 qv = *(const u32*)(q_buf + gbase);
        float x0 = b2f(qv & 0xffffu), x1 = b2f(qv >> 16);
        *(u32*)&qs[row * 72 + 2 * i] = pack2(x0 * c - x1 * s, x1 * c + x0 * s);
        u32 kv = *(const u32*)(k_buf + gbase);
        x0 = b2f(kv & 0xffffu); x1 = b2f(kv >> 16);
        *(u32*)&ks[(row + 4) * 72 + 2 * i] = pack2(x0 * c - x1 * s, x1 * c + x0 * s);
    }
    // stage V transposed (u32 global loads, two u16 LDS stores)
#pragma unroll
    for (int p = tid; p < 2048; p += 256) {
        int row = p >> 5, e = p & 31;
        u32 vv = *(const u32*)(v_buf + (size_t)(t0 + row) * 512 + h * 64 + 2 * e);
        vt[(2 * e) * 104 + 4 + row]     = (u16)(vv & 0xffffu);
        vt[(2 * e + 1) * 104 + 4 + row] = (u16)(vv >> 16);
    }
    __syncthreads();

    // S = Q K^T (wave w owns q-rows [w*16, w*16+16))
    f32x4 sacc[5];
#pragma unroll
    for (int nt = 0; nt < 5; ++nt) sacc[nt] = (f32x4){0.f, 0.f, 0.f, 0.f};
#pragma unroll
    for (int ksi = 0; ksi < 2; ++ksi) {
        short8 a = *(const short8*)&qs[(w * 16 + l15) * 72 + ksi * 32 + l4 * 8];
#pragma unroll
        for (int nt = 0; nt < 5; ++nt) {
            short8 bfr = *(const short8*)&ks[(nt * 16 + l15) * 72 + ksi * 32 + l4 * 8];
            sacc[nt] = __builtin_amdgcn_mfma_f32_16x16x32_bf16(a, bfr, sacc[nt], 0, 0, 0);
        }
    }
    // softmax (rows = w*16 + l4*4 + r; cols spread over 16 lanes x 5 tiles)
    float inv_l[4];
#pragma unroll
    for (int r = 0; r < 4; ++r) {
        float sv[5];
#pragma unroll
        for (int nt = 0; nt < 5; ++nt) {
            float x = sacc[nt][r] * 0.125f;
            if (nt == 4 && l15 >= 4) x = -1e30f;   // keys >= 68 masked
            sv[nt] = x;
        }
        float m = sv[0];
#pragma unroll
        for (int nt = 1; nt < 5; ++nt) m = fmaxf(m, sv[nt]);
#pragma unroll
        for (int off = 1; off < 16; off <<= 1) m = fmaxf(m, __shfl_xor(m, off));
        float sum = 0.f;
#pragma unroll
        for (int nt = 0; nt < 5; ++nt) { sv[nt] = __expf(sv[nt] - m); sum += sv[nt]; }
#pragma unroll
        for (int off = 1; off < 16; off <<= 1) sum += __shfl_xor(sum, off);
        inv_l[r] = 1.f / sum;
        int prow = w * 16 + l4 * 4 + r;
#pragma unroll
        for (int nt = 0; nt < 5; ++nt) ps[prow * 104 + nt * 16 + l15] = f2b(sv[nt]);
        ps[prow * 104 + 80 + l15] = 0;   // pad keys 80..95 for the ksi=2 PV step
    }
    __syncthreads();

    // O = P V  (K-dim padded to 96)
    f32x4 oacc[4];
#pragma unroll
    for (int dt = 0; dt < 4; ++dt) oacc[dt] = (f32x4){0.f, 0.f, 0.f, 0.f};
#pragma unroll
    for (int ksi = 0; ksi < 3; ++ksi) {
        short8 a = *(const short8*)&ps[(w * 16 + l15) * 104 + ksi * 32 + l4 * 8];
#pragma unroll
        for (int dt = 0; dt < 4; ++dt) {
            short8 bfr = *(const short8*)&vt[(dt * 16 + l15) * 104 + ksi * 32 + l4 * 8];
            oacc[dt] = __builtin_amdgcn_mfma_f32_16x16x32_bf16(a, bfr, oacc[dt], 0, 0, 0);
        }
    }
#pragma unroll
    for (int dt = 0; dt < 4; ++dt)
#pragma unroll
        for (int r = 0; r < 4; ++r) {
            int row = w * 16 + l4 * 4 + r;
            o_buf[(size_t)(t0 + row) * 512 + h * 64 + dt * 16 + l15] =
                f2b(oacc[dt][r] * inv_l[r]);
        }
}

// ---------------- launch ----------------
extern "C" void kernel_launch(void* const* d_in, const int* in_sizes, int n_in,
                              void* d_out, int out_size, void* d_ws, size_t ws_size,
                              hipStream_t stream) {
    const float* seq    = (const float*)d_in[0];
    const float* norm_w = (const float*)d_in[5];
    const float* Wq     = (const float*)d_in[6];
    const float* Wkv    = (const float*)d_in[7];
    const float* Wo     = (const float*)d_in[8];
    const float* tmem   = (const float*)d_in[9];
    float* out   = (float*)d_out;
    float* origv = out + 33554432;          // (B=4, h=8, N=16384, d=64)

    char* ws = (char*)d_ws;
    u16* xn    = (u16*)(ws);                 // 64 MB; reused as attn_out after qkv GEMM
    u16* q_buf = (u16*)(ws + 67108864);
    u16* k_buf = (u16*)(ws + 134217728);
    u16* v_buf = (u16*)(ws + 201326592);
    u16* wqkvT = (u16*)(ws + 268435456);     // 1536x512 bf16
    u16* woT   = (u16*)(ws + 268435456 + 1572864);   // 512x512 bf16
    float* cosT = (float*)(ws + 270532608);  // 16384x32
    float* sinT = cosT + 524288;

    rope_tab<<<2048, 256, 0, stream>>>(cosT, sinT);
    conv_w<<<4096, 256, 0, stream>>>(Wq, Wkv, Wo, wqkvT, woT);
    rmsnorm_k<<<16384, 256, 0, stream>>>(seq, norm_w, xn);
    gemm_k512<0><<<6144, 256, 0, stream>>>(xn, wqkvT, q_buf, k_buf, v_buf, origv);
    attn_win<<<dim3(8, 256, 4), 256, 0, stream>>>(q_buf, k_buf, v_buf, tmem, cosT, sinT, xn);
    gemm_k512<1><<<2048, 256, 0, stream>>>(xn, woT, nullptr, nullptr, nullptr, out);
}